// Round 5
// baseline (103.174 us; speedup 1.0000x reference)
//
#include <hip/hip_runtime.h>
#include <math.h>

// TripletLoss N=8192, D=128, labels in [0,512). Round 8: counted-vmcnt ring.
//   histscan: 1 block — int4 hist + wave-shuffle scan.
//   scatter:  permute rows into label-sorted order.
//   pair:     LDS ring of 4 x 32-row subtiles, depth-2 prefetch via
//             global_load_lds w=16; raw s_barrier + s_waitcnt vmcnt(4)
//             (NEVER 0 in steady state) so stage loads span barriers
//             (T3+T4, m218: counted-vs-drain0 = +38..73%). XOR swizzle
//             (row&15)<<4 on both sides (rule 21). Fast/slow epilogue via
//             16-bit tile-overlap masks (sorted labels -> ~99% fast).
//   reduce:   min/max over JSPLIT partials + fused final via done-ticket.
// Ring safety: iter s issues stage(s+2)->buf[(s+2)&3]; every wave's read of
// buf[(s-2)&3] finished before the iter-(s-1) barrier, which precedes the
// issue. vmcnt(4) at iter s guarantees own stage(s) loads retired (2 loads
// per stage per wave, <=2 stages in flight); barrier extends to all waves.
// Note: harness poisons the 256MB workspace (~42us fillBuffer) inside the
// timed window every iteration — a floor we don't control.
// Self-pair never wins hp (u_self = +0.5*sq is max-u; hp takes min-u);
// validity = hist[lab]>=2 && hist[lab]<N, matching the reference mask.

#define NROWS 8192
#define DIM   128
#define NLAB  512
#define JSPLIT 32
#define JCHUNK (NROWS / JSPLIT)   // 256 j per y-block
#define NSUBT  8                  // 32-row subtiles per j-chunk
#define SUBROWS 32

typedef short bf16x8 __attribute__((ext_vector_type(8)));
typedef float f32x4  __attribute__((ext_vector_type(4)));

static __device__ __forceinline__ unsigned short f2bf(float f) {
    unsigned u = __float_as_uint(f);
    unsigned r = (u + 0x7FFFu + ((u >> 16) & 1u)) >> 16;   // RNE
    return (unsigned short)r;
}

static __device__ __forceinline__ void gload_lds16(const void* g, void* l) {
    __builtin_amdgcn_global_load_lds(
        (const __attribute__((address_space(1))) unsigned int*)g,
        (__attribute__((address_space(3))) unsigned int*)l, 16, 0, 0);
}

// ---------------- K1: hist + exclusive scan + zero accumulators ----------
__global__ __launch_bounds__(512) void histscan_kernel(
    const int* __restrict__ labels, int* __restrict__ hist,
    int* __restrict__ base, int* __restrict__ cursor,
    float* __restrict__ gsum, float* __restrict__ gcnt,
    unsigned* __restrict__ done) {
    __shared__ int h[NLAB];
    __shared__ int wpre[8];
    int t = threadIdx.x;
    h[t] = 0;
    __syncthreads();
    const int4* l4 = (const int4*)labels;
#pragma unroll
    for (int i = 0; i < NROWS / 4 / 512; ++i) {
        int4 L = l4[i * 512 + t];
        atomicAdd(&h[L.x], 1); atomicAdd(&h[L.y], 1);
        atomicAdd(&h[L.z], 1); atomicAdd(&h[L.w], 1);
    }
    __syncthreads();
    int v = h[t];
    int sc = v;                       // inclusive scan within wave
#pragma unroll
    for (int d = 1; d < 64; d <<= 1) {
        int y = __shfl_up(sc, d, 64);
        if ((t & 63) >= d) sc += y;
    }
    if ((t & 63) == 63) wpre[t >> 6] = sc;
    __syncthreads();
    if (t < 8) {                      // scan the 8 wave sums
        int w = wpre[t];
        int p = w;
#pragma unroll
        for (int d = 1; d < 8; d <<= 1) {
            int y = __shfl_up(p, d, 64);
            if (t >= d) p += y;
        }
        wpre[t] = p - w;              // exclusive
    }
    __syncthreads();
    int incl = sc + wpre[t >> 6];
    int b = incl - v;                 // exclusive prefix
    hist[t] = v;
    base[t] = b;
    cursor[t] = b;
    if (t == 0) { *gsum = 0.f; *gcnt = 0.f; *done = 0u; }
}

// ---------------- K2: bucketed scatter + bf16 convert + sq ---------------
__global__ __launch_bounds__(256) void scatter_kernel(
    const float* __restrict__ x, const int* __restrict__ labels,
    const int* __restrict__ base, const int* __restrict__ hist,
    int* __restrict__ cursor, float* __restrict__ sqp,
    float* __restrict__ sqh, int* __restrict__ labp,
    int2* __restrict__ rng, unsigned short* __restrict__ xb) {
    int t = blockIdx.x * 256 + threadIdx.x;
    int row = t >> 5;
    int c = t & 31;
    int wl = threadIdx.x & 63;
    float4 v = ((const float4*)x)[t];
    float ps = v.x * v.x + v.y * v.y + v.z * v.z + v.w * v.w;
#pragma unroll
    for (int sft = 1; sft < 32; sft <<= 1) ps += __shfl_xor(ps, sft, 64);
    int p;
    if (c == 0) {
        int l = labels[row];
        p = atomicAdd(&cursor[l], 1);
        sqp[p] = ps;
        sqh[p] = -0.5f * ps;
        labp[p] = l;
        rng[p] = make_int2(base[l], base[l] + hist[l]);
    }
    p = __shfl(p, wl & 32, 64);     // broadcast from lane 0 / lane 32
    ushort4 ob;
    ob.x = f2bf(v.x); ob.y = f2bf(v.y); ob.z = f2bf(v.z); ob.w = f2bf(v.w);
    ((ushort4*)xb)[p * 32 + c] = ob;
}

// ---------------- K3: pair kernel (counted-vmcnt ring) -------------------
__global__ __launch_bounds__(256, 4) void pair_kernel(
    const unsigned short* __restrict__ xb, const float* __restrict__ sqh,
    const int* __restrict__ labp, const int2* __restrict__ rng,
    float* __restrict__ hpp, float* __restrict__ hnp) {
    // 4-deep ring of swizzled 32-row subtiles + staged -0.5*sq_j
    __shared__ __attribute__((aligned(16))) unsigned char abuf[4][SUBROWS * 256];
    __shared__ __attribute__((aligned(16))) float sqs[JCHUNK];

    const int tid = threadIdx.x;
    const int lane = tid & 63;
    const int wid = tid >> 6;        // 0..3
    const int q = lane >> 4;         // 0..3
    const int r = lane & 15;
    const int ibase = blockIdx.x * 256 + wid * 64;
    const int jbase = blockIdx.y * JCHUNK;

    sqs[tid] = sqh[jbase + tid];

    // B-frags (i side), resident for the whole j-loop.
    bf16x8 bfrag[4][4];
    unsigned ovm[4];                 // per-sub 16-bit tile-overlap masks
#pragma unroll
    for (int sub = 0; sub < 4; ++sub) {
        int irow = ibase + sub * 16 + r;
        int2 g = rng[irow];
        int a = g.x - jbase;         // positive range rel. to chunk
        int b = g.y - jbase;
        int ttmin = a >> 4;
        if (ttmin < 0) ttmin = 0;
        if (ttmin > 16) ttmin = 16;  // keep shift amounts defined
        int ttmax = (b - 1) >> 4;
        if (ttmax > 15) ttmax = 15;
        ovm[sub] = (ttmax >= ttmin) ? ((2u << ttmax) - (1u << ttmin)) : 0u;
#pragma unroll
        for (int ks = 0; ks < 4; ++ks)
            bfrag[sub][ks] = *(const bf16x8*)(xb + (size_t)irow * DIM + ks * 32 + q * 8);
    }
    const unsigned ovu = ovm[0] | ovm[1] | ovm[2] | ovm[3];

    float hp[4] = {INFINITY, INFINITY, INFINITY, INFINITY};     // min u (pos)
    float hn[4] = {-INFINITY, -INFINITY, -INFINITY, -INFINITY}; // max u (neg)

    // Stage subtile s (32 rows x 128 bf16 = 8 KB), swizzled source (rule 21):
    // LDS[row][c] = G[row][c ^ ((row&15)<<4)], linear gload_lds dest.
    auto stage = [&](int s, int buf) {
        const char* gb = (const char*)xb + (size_t)(jbase + s * SUBROWS) * 256;
        unsigned char* lb = &abuf[buf][0];
#pragma unroll
        for (int p = 0; p < 2; ++p) {
            int row = wid * 8 + p * 4 + (lane >> 4);
            int colb = (lane & 15) * 16;
            const void* g = gb + row * 256 + (colb ^ ((row & 15) << 4));
            void* l = lb + wid * 2048 + p * 1024;   // wave-uniform base
            gload_lds16(g, l);
        }
    };

    auto compute_tile = [&](int s, int buf, int t) {
        const unsigned char* lb = &abuf[buf][0];
        const int tt = s * 2 + t;    // 16-row tile index within chunk, 0..15
        bf16x8 af[4];
        const int rowb = (t * 16 + r) * 256;
        const int sw = r << 4;       // (row&15)<<4, row = t*16+r
#pragma unroll
        for (int ks = 0; ks < 4; ++ks)
            af[ks] = *(const bf16x8*)(lb + rowb + ((ks * 64 + q * 16) ^ sw));
        f32x4 ci = *(const f32x4*)(&sqs[tt * 16 + q * 4]);

        if (!__any((int)((ovu >> tt) & 1u))) {
            // FAST: tile is all-negatives for every i here.
#pragma unroll
            for (int sub = 0; sub < 4; ++sub) {
                f32x4 acc = ci;
                acc = __builtin_amdgcn_mfma_f32_16x16x32_bf16(af[0], bfrag[sub][0], acc, 0, 0, 0);
                acc = __builtin_amdgcn_mfma_f32_16x16x32_bf16(af[1], bfrag[sub][1], acc, 0, 0, 0);
                acc = __builtin_amdgcn_mfma_f32_16x16x32_bf16(af[2], bfrag[sub][2], acc, 0, 0, 0);
                acc = __builtin_amdgcn_mfma_f32_16x16x32_bf16(af[3], bfrag[sub][3], acc, 0, 0, 0);
                hn[sub] = fmaxf(hn[sub],
                                fmaxf(fmaxf(acc[0], acc[1]), fmaxf(acc[2], acc[3])));
            }
        } else {
            // SLOW (rare): exact per-element label masking.
            const int j0 = jbase + tt * 16;
            int4 labj = *(const int4*)(labp + j0 + q * 4);
#pragma unroll
            for (int sub = 0; sub < 4; ++sub) {
                f32x4 acc = ci;
                acc = __builtin_amdgcn_mfma_f32_16x16x32_bf16(af[0], bfrag[sub][0], acc, 0, 0, 0);
                acc = __builtin_amdgcn_mfma_f32_16x16x32_bf16(af[1], bfrag[sub][1], acc, 0, 0, 0);
                acc = __builtin_amdgcn_mfma_f32_16x16x32_bf16(af[2], bfrag[sub][2], acc, 0, 0, 0);
                acc = __builtin_amdgcn_mfma_f32_16x16x32_bf16(af[3], bfrag[sub][3], acc, 0, 0, 0);
                if (__any((int)((ovm[sub] >> tt) & 1u))) {
                    const int li = labp[ibase + sub * 16 + r];
                    float u0 = acc[0], u1 = acc[1], u2 = acc[2], u3 = acc[3];
                    hp[sub] = fminf(hp[sub], (labj.x == li) ? u0 : INFINITY);
                    hn[sub] = fmaxf(hn[sub], (labj.x == li) ? -INFINITY : u0);
                    hp[sub] = fminf(hp[sub], (labj.y == li) ? u1 : INFINITY);
                    hn[sub] = fmaxf(hn[sub], (labj.y == li) ? -INFINITY : u1);
                    hp[sub] = fminf(hp[sub], (labj.z == li) ? u2 : INFINITY);
                    hn[sub] = fmaxf(hn[sub], (labj.z == li) ? -INFINITY : u2);
                    hp[sub] = fminf(hp[sub], (labj.w == li) ? u3 : INFINITY);
                    hn[sub] = fmaxf(hn[sub], (labj.w == li) ? -INFINITY : u3);
                } else {
                    hn[sub] = fmaxf(hn[sub],
                                    fmaxf(fmaxf(acc[0], acc[1]), fmaxf(acc[2], acc[3])));
                }
            }
        }
    };

    // Prologue: fill ring slots 0,1; one full drain (__syncthreads also
    // publishes sqs and retires bfrag loads). Steady loop never drains.
    stage(0, 0);
    stage(1, 1);
    __syncthreads();

#define PAIR_ITER(S, VMSTR)                                              \
    {                                                                    \
        if ((S) + 2 < NSUBT) stage((S) + 2, ((S) + 2) & 3);              \
        asm volatile("s_waitcnt " VMSTR ::: "memory");                   \
        __builtin_amdgcn_s_barrier();                                    \
        __builtin_amdgcn_sched_barrier(0);                               \
        compute_tile((S), (S) & 3, 0);                                   \
        compute_tile((S), (S) & 3, 1);                                   \
    }

    PAIR_ITER(0, "vmcnt(4)")
    PAIR_ITER(1, "vmcnt(4)")
    PAIR_ITER(2, "vmcnt(4)")
    PAIR_ITER(3, "vmcnt(4)")
    PAIR_ITER(4, "vmcnt(4)")
    PAIR_ITER(5, "vmcnt(4)")
    PAIR_ITER(6, "vmcnt(2)")
    PAIR_ITER(7, "vmcnt(0)")
#undef PAIR_ITER

    // reduce across the 4 q-groups (lanes r, r+16, r+32, r+48)
#pragma unroll
    for (int sub = 0; sub < 4; ++sub) {
        hp[sub] = fminf(hp[sub], __shfl_xor(hp[sub], 16, 64));
        hp[sub] = fminf(hp[sub], __shfl_xor(hp[sub], 32, 64));
        hn[sub] = fmaxf(hn[sub], __shfl_xor(hn[sub], 16, 64));
        hn[sub] = fmaxf(hn[sub], __shfl_xor(hn[sub], 32, 64));
    }
    if (lane < 16) {
        const int pbase = blockIdx.y * NROWS;
#pragma unroll
        for (int sub = 0; sub < 4; ++sub) {
            int irow = ibase + sub * 16 + lane;
            hpp[pbase + irow] = hp[sub];
            hnp[pbase + irow] = hn[sub];
        }
    }
}

// ---------------- K4: reduce + fused final ------------------------------
__global__ __launch_bounds__(256) void reduce_kernel(
    const float* __restrict__ hpp, const float* __restrict__ hnp,
    const float* __restrict__ sqp, const int* __restrict__ labp,
    const int* __restrict__ hist, float* __restrict__ gsum,
    float* __restrict__ gcnt, unsigned* __restrict__ done,
    float* __restrict__ out) {
    int row = blockIdx.x * 256 + threadIdx.x;
    float mnp = INFINITY, mxn = -INFINITY;
#pragma unroll 8
    for (int p = 0; p < JSPLIT; ++p) {
        mnp = fminf(mnp, hpp[p * NROWS + row]);
        mxn = fmaxf(mxn, hnp[p * NROWS + row]);
    }
    float s = sqp[row];
    int h = hist[labp[row]];
    float sum = 0.f, cnt = 0.f;
    if (h >= 2 && h < NROWS) {
        float dp = sqrtf(fmaxf(s - 2.f * mnp, 1e-12f));
        float dn = sqrtf(fmaxf(s - 2.f * mxn, 1e-12f));
        sum = fmaxf(dp - dn + 0.3f, 1e-6f);
        cnt = 1.f;
    }
#pragma unroll
    for (int sh = 1; sh < 64; sh <<= 1) {
        sum += __shfl_xor(sum, sh, 64);
        cnt += __shfl_xor(cnt, sh, 64);
    }
    __shared__ float ss[4], sc[4];
    int w = threadIdx.x >> 6;
    if ((threadIdx.x & 63) == 0) { ss[w] = sum; sc[w] = cnt; }
    __syncthreads();
    if (threadIdx.x == 0) {
        atomicAdd(gsum, ss[0] + ss[1] + ss[2] + ss[3]);
        atomicAdd(gcnt, sc[0] + sc[1] + sc[2] + sc[3]);
        __threadfence();
        unsigned t = atomicAdd(done, 1u);
        if (t == gridDim.x - 1) {
            float S = atomicAdd(gsum, 0.f);   // coherent read via RMW
            float C = atomicAdd(gcnt, 0.f);
            out[0] = (C > 0.f) ? S / C : 0.f;
        }
    }
}

extern "C" void kernel_launch(void* const* d_in, const int* in_sizes, int n_in,
                              void* d_out, int out_size, void* d_ws, size_t ws_size,
                              hipStream_t stream) {
    const float* x = (const float*)d_in[0];
    const int* labels = (const int*)d_in[1];
    float* out = (float*)d_out;

    // ws layout:
    //   hist   @ 0        (2 KB)
    //   base   @ 2048     (2 KB)
    //   cursor @ 4096     (2 KB)
    //   gsum   @ 6144, gcnt @ 6148, done @ 6152
    //   sqp    @ 8192     (32 KB)
    //   sqh    @ 40960    (32 KB)   -0.5*sq, pair cinit
    //   labp   @ 73728    (32 KB)
    //   rng    @ 106496   (64 KB int2)
    //   hpp    @ 172032   (1 MB)  [JSPLIT x NROWS]
    //   hnp    @ 1220608  (1 MB)
    //   xb     @ 2269184  (2 MB bf16)      total ~4.37 MB
    char* ws = (char*)d_ws;
    int* hist = (int*)ws;
    int* base = (int*)(ws + 2048);
    int* cursor = (int*)(ws + 4096);
    float* gsum = (float*)(ws + 6144);
    float* gcnt = (float*)(ws + 6148);
    unsigned* done = (unsigned*)(ws + 6152);
    float* sqp = (float*)(ws + 8192);
    float* sqh = (float*)(ws + 40960);
    int* labp = (int*)(ws + 73728);
    int2* rng = (int2*)(ws + 106496);
    float* hpp = (float*)(ws + 172032);
    float* hnp = (float*)(ws + 1220608);
    unsigned short* xb = (unsigned short*)(ws + 2269184);

    histscan_kernel<<<1, 512, 0, stream>>>(labels, hist, base, cursor, gsum, gcnt, done);
    scatter_kernel<<<(NROWS * 32) / 256, 256, 0, stream>>>(
        x, labels, base, hist, cursor, sqp, sqh, labp, rng, xb);
    pair_kernel<<<dim3(NROWS / 256, JSPLIT), 256, 0, stream>>>(
        xb, sqh, labp, rng, hpp, hnp);
    reduce_kernel<<<NROWS / 256, 256, 0, stream>>>(
        hpp, hnp, sqp, labp, hist, gsum, gcnt, done, out);
}

// Round 6
// 94.564 us; speedup vs baseline: 1.0910x; 1.0910x over previous
//
#include <hip/hip_runtime.h>
#include <math.h>

// TripletLoss N=8192, D=128, labels in [0,512). Round 9: minimal front-end.
//   Lesson from r6-r8: pair-structure edits (residency, swizzle, counted
//   vmcnt) were all neutral — pair sits at its structural ~27-30us. The
//   OTHER ~30us (histscan 1-block + scatter + fat reduce + gaps) is the
//   same size. This round deletes the bucketing apparatus entirely:
//   memset(4KB): zero hist/gsum/gcnt/done  (poison-safe accumulators).
//   prep:   sq, -0.5sq, bf16 cast, global-atomic hist, init of the
//           global min/max encoding arrays (round-0-proven pattern).
//   pair:   round-7 core (LDS dbuf 64-row, 2 barriers, (row&15)<<4
//           swizzle both sides, 4 blocks/CU). Labels staged to LDS;
//           every tile uses the exact per-element masked epilogue.
//           Per-row results merged via global atomicMin/Max on
//           order-preserving uint encodings — no 2MB partial arrays.
//   reduce: 32 blocks, 1 row/thread: decode, validity, sqrt+margin,
//           block sums -> gsum/gcnt atomics, done-ticket final -> out.
// Exactness: min/max are order-independent; all arithmetic (bf16 RNE,
// MFMA order, sqrt/margin) identical to the previously-passing rounds.
// Self-pair never wins hp: u_self=+0.5*sq_i is the max-u among positives
// (d^2>=0 => u_ij <= 0.5 sq_i); rows with hist<2 are invalid anyway.
// Note: harness poisons the 256MB workspace (~42us fillBuffer) inside the
// timed window every iteration — a floor we don't control.

#define NROWS 8192
#define DIM   128
#define JSPLIT 32
#define JCHUNK (NROWS / JSPLIT)   // 256 j per y-block
#define NSUB   4                  // 64-row subtiles per j-chunk
#define SUBROWS 64

typedef short bf16x8 __attribute__((ext_vector_type(8)));
typedef float f32x4  __attribute__((ext_vector_type(4)));

static __device__ __forceinline__ unsigned short f2bf(float f) {
    unsigned u = __float_as_uint(f);
    unsigned r = (u + 0x7FFFu + ((u >> 16) & 1u)) >> 16;   // RNE
    return (unsigned short)r;
}

// order-preserving float<->uint encoding: unsigned compare == float compare
static __device__ __forceinline__ unsigned encf(float f) {
    unsigned u = __float_as_uint(f);
    return (u & 0x80000000u) ? ~u : (u | 0x80000000u);
}
static __device__ __forceinline__ float decf(unsigned e) {
    unsigned u = (e & 0x80000000u) ? (e & 0x7FFFFFFFu) : ~e;
    return __uint_as_float(u);
}
#define ENC_PINF 0xFF800000u   // encf(+INF) — init for min
#define ENC_NINF 0x007FFFFFu   // encf(-INF) — init for max

static __device__ __forceinline__ void gload_lds16(const void* g, void* l) {
    __builtin_amdgcn_global_load_lds(
        (const __attribute__((address_space(1))) unsigned int*)g,
        (__attribute__((address_space(3))) unsigned int*)l, 16, 0, 0);
}

// ---------------- K1: prep — sq, bf16, hist, minmax init ----------------
// one thread per float4 chunk: 8192*32 = 262144 threads
__global__ __launch_bounds__(256) void prep_kernel(
    const float* __restrict__ x, const int* __restrict__ labels,
    int* __restrict__ hist, float* __restrict__ sqp,
    float* __restrict__ sqh, unsigned* __restrict__ hpE,
    unsigned* __restrict__ hnE, unsigned short* __restrict__ xb) {
    int t = blockIdx.x * 256 + threadIdx.x;
    int row = t >> 5;
    int c = t & 31;
    float4 v = ((const float4*)x)[t];
    float ps = v.x * v.x + v.y * v.y + v.z * v.z + v.w * v.w;
#pragma unroll
    for (int s = 1; s < 32; s <<= 1) ps += __shfl_xor(ps, s, 64);
    if (c == 0) {
        sqp[row] = ps;
        sqh[row] = -0.5f * ps;
        atomicAdd(&hist[labels[row]], 1);
    } else if (c == 1) {
        hpE[row] = ENC_PINF;
    } else if (c == 2) {
        hnE[row] = ENC_NINF;
    }
    ushort4 ob;
    ob.x = f2bf(v.x); ob.y = f2bf(v.y); ob.z = f2bf(v.z); ob.w = f2bf(v.w);
    ((ushort4*)xb)[t] = ob;
}

// ---------------- K2: pair kernel (LDS dbuf, atomic merge) ---------------
__global__ __launch_bounds__(256, 4) void pair_kernel(
    const unsigned short* __restrict__ xb, const float* __restrict__ sqh,
    const int* __restrict__ labels,
    unsigned* __restrict__ hpE, unsigned* __restrict__ hnE) {
    __shared__ __attribute__((aligned(16))) unsigned char abuf[2][SUBROWS * 256];
    __shared__ __attribute__((aligned(16))) float sqs[JCHUNK];
    __shared__ __attribute__((aligned(16))) int labs[JCHUNK];

    const int tid = threadIdx.x;
    const int lane = tid & 63;
    const int wid = tid >> 6;        // 0..3
    const int q = lane >> 4;         // 0..3
    const int r = lane & 15;
    const int ibase = blockIdx.x * 256 + wid * 64;
    const int jbase = blockIdx.y * JCHUNK;

    sqs[tid] = sqh[jbase + tid];     // -0.5*sq_j
    labs[tid] = labels[jbase + tid];

    // B-frags (i side), resident for the whole j-loop.
    bf16x8 bfrag[4][4];
    int labi[4];
#pragma unroll
    for (int sub = 0; sub < 4; ++sub) {
        int irow = ibase + sub * 16 + r;
        labi[sub] = labels[irow];
#pragma unroll
        for (int ks = 0; ks < 4; ++ks)
            bfrag[sub][ks] = *(const bf16x8*)(xb + (size_t)irow * DIM + ks * 32 + q * 8);
    }

    float hp[4] = {INFINITY, INFINITY, INFINITY, INFINITY};     // min u (pos)
    float hn[4] = {-INFINITY, -INFINITY, -INFINITY, -INFINITY}; // max u (neg)

    // Stage subtile s (64 rows x 128 bf16 = 16 KB), swizzled source
    // (rule 21): LDS[row][c] = G[row][c ^ ((row&15)<<4)], linear dest.
    auto stage = [&](int s, int buf) {
        const char* gb = (const char*)xb + (size_t)(jbase + s * SUBROWS) * 256;
        unsigned char* lb = &abuf[buf][0];
#pragma unroll
        for (int p = 0; p < 4; ++p) {
            int row = wid * 16 + p * 4 + (lane >> 4);
            int colb = (lane & 15) * 16;
            const void* g = gb + row * 256 + (colb ^ ((row & 15) << 4));
            void* l = lb + wid * 4096 + p * 1024;   // wave-uniform base
            gload_lds16(g, l);
        }
    };

    auto compute_tile = [&](int s, int buf, int t) {
        const unsigned char* lb = &abuf[buf][0];
        const int tt = s * 4 + t;    // 16-row tile index within chunk, 0..15
        bf16x8 af[4];
        const int rowb = (t * 16 + r) * 256;
        const int sw = r << 4;       // (row&15)<<4, row = t*16+r
#pragma unroll
        for (int ks = 0; ks < 4; ++ks)
            af[ks] = *(const bf16x8*)(lb + rowb + ((ks * 64 + q * 16) ^ sw));
        f32x4 ci = *(const f32x4*)(&sqs[tt * 16 + q * 4]);
        int4 labj = *(const int4*)(labs + tt * 16 + q * 4);
#pragma unroll
        for (int sub = 0; sub < 4; ++sub) {
            f32x4 acc = ci;
            acc = __builtin_amdgcn_mfma_f32_16x16x32_bf16(af[0], bfrag[sub][0], acc, 0, 0, 0);
            acc = __builtin_amdgcn_mfma_f32_16x16x32_bf16(af[1], bfrag[sub][1], acc, 0, 0, 0);
            acc = __builtin_amdgcn_mfma_f32_16x16x32_bf16(af[2], bfrag[sub][2], acc, 0, 0, 0);
            acc = __builtin_amdgcn_mfma_f32_16x16x32_bf16(af[3], bfrag[sub][3], acc, 0, 0, 0);
            const int li = labi[sub];
            float u0 = acc[0], u1 = acc[1], u2 = acc[2], u3 = acc[3];
            hp[sub] = fminf(hp[sub], (labj.x == li) ? u0 : INFINITY);
            hn[sub] = fmaxf(hn[sub], (labj.x == li) ? -INFINITY : u0);
            hp[sub] = fminf(hp[sub], (labj.y == li) ? u1 : INFINITY);
            hn[sub] = fmaxf(hn[sub], (labj.y == li) ? -INFINITY : u1);
            hp[sub] = fminf(hp[sub], (labj.z == li) ? u2 : INFINITY);
            hn[sub] = fmaxf(hn[sub], (labj.z == li) ? -INFINITY : u2);
            hp[sub] = fminf(hp[sub], (labj.w == li) ? u3 : INFINITY);
            hn[sub] = fmaxf(hn[sub], (labj.w == li) ? -INFINITY : u3);
        }
    };

    // m97 two-barrier pipeline: stage(s+1) in flight while computing s.
    // First barrier also publishes sqs/labs.
    stage(0, 0);
    __syncthreads();
#pragma unroll
    for (int s = 0; s < NSUB; ++s) {
        if (s + 1 < NSUB) stage(s + 1, (s + 1) & 1);
#pragma unroll
        for (int t = 0; t < 4; ++t) compute_tile(s, s & 1, t);
        __syncthreads();
    }

    // reduce across the 4 q-groups (lanes r, r+16, r+32, r+48)
#pragma unroll
    for (int sub = 0; sub < 4; ++sub) {
        hp[sub] = fminf(hp[sub], __shfl_xor(hp[sub], 16, 64));
        hp[sub] = fminf(hp[sub], __shfl_xor(hp[sub], 32, 64));
        hn[sub] = fmaxf(hn[sub], __shfl_xor(hn[sub], 16, 64));
        hn[sub] = fmaxf(hn[sub], __shfl_xor(hn[sub], 32, 64));
    }
    if (lane < 16) {
#pragma unroll
        for (int sub = 0; sub < 4; ++sub) {
            int irow = ibase + sub * 16 + lane;
            atomicMin(&hpE[irow], encf(hp[sub]));
            atomicMax(&hnE[irow], encf(hn[sub]));
        }
    }
}

// ---------------- K3: reduce + fused final ------------------------------
__global__ __launch_bounds__(256) void reduce_kernel(
    const unsigned* __restrict__ hpE, const unsigned* __restrict__ hnE,
    const float* __restrict__ sqp, const int* __restrict__ labels,
    const int* __restrict__ hist, float* __restrict__ gsum,
    float* __restrict__ gcnt, unsigned* __restrict__ done,
    float* __restrict__ out) {
    int row = blockIdx.x * 256 + threadIdx.x;
    float mnp = decf(hpE[row]);
    float mxn = decf(hnE[row]);
    float s = sqp[row];
    int h = hist[labels[row]];
    float sum = 0.f, cnt = 0.f;
    if (h >= 2 && h < NROWS) {
        float dp = sqrtf(fmaxf(s - 2.f * mnp, 1e-12f));
        float dn = sqrtf(fmaxf(s - 2.f * mxn, 1e-12f));
        sum = fmaxf(dp - dn + 0.3f, 1e-6f);
        cnt = 1.f;
    }
#pragma unroll
    for (int sh = 1; sh < 64; sh <<= 1) {
        sum += __shfl_xor(sum, sh, 64);
        cnt += __shfl_xor(cnt, sh, 64);
    }
    __shared__ float ss[4], sc[4];
    int w = threadIdx.x >> 6;
    if ((threadIdx.x & 63) == 0) { ss[w] = sum; sc[w] = cnt; }
    __syncthreads();
    if (threadIdx.x == 0) {
        atomicAdd(gsum, ss[0] + ss[1] + ss[2] + ss[3]);
        atomicAdd(gcnt, sc[0] + sc[1] + sc[2] + sc[3]);
        __threadfence();
        unsigned t = atomicAdd(done, 1u);
        if (t == gridDim.x - 1) {
            float S = atomicAdd(gsum, 0.f);   // coherent read via RMW
            float C = atomicAdd(gcnt, 0.f);
            out[0] = (C > 0.f) ? S / C : 0.f;
        }
    }
}

extern "C" void kernel_launch(void* const* d_in, const int* in_sizes, int n_in,
                              void* d_out, int out_size, void* d_ws, size_t ws_size,
                              hipStream_t stream) {
    const float* x = (const float*)d_in[0];
    const int* labels = (const int*)d_in[1];
    float* out = (float*)d_out;

    // ws layout:
    //   hist @ 0      (2 KB)  \
    //   gsum @ 2048, gcnt @ 2052, done @ 2056   } zeroed by one 4KB memset
    //   sqp  @ 4096   (32 KB)
    //   sqh  @ 36864  (32 KB)   -0.5*sq (pair cinit)
    //   hpE  @ 69632  (32 KB)   encoded min-u (positives)
    //   hnE  @ 102400 (32 KB)   encoded max-u (negatives)
    //   xb   @ 135168 (2 MB bf16)      total ~2.2 MB
    char* ws = (char*)d_ws;
    int* hist = (int*)ws;
    float* gsum = (float*)(ws + 2048);
    float* gcnt = (float*)(ws + 2052);
    unsigned* done = (unsigned*)(ws + 2056);
    float* sqp = (float*)(ws + 4096);
    float* sqh = (float*)(ws + 36864);
    unsigned* hpE = (unsigned*)(ws + 69632);
    unsigned* hnE = (unsigned*)(ws + 102400);
    unsigned short* xb = (unsigned short*)(ws + 135168);

    hipMemsetAsync(ws, 0, 4096, stream);
    prep_kernel<<<(NROWS * 32) / 256, 256, 0, stream>>>(
        x, labels, hist, sqp, sqh, hpE, hnE, xb);
    pair_kernel<<<dim3(NROWS / 256, JSPLIT), 256, 0, stream>>>(
        xb, sqh, labels, hpE, hnE);
    reduce_kernel<<<NROWS / 256, 256, 0, stream>>>(
        hpE, hnE, sqp, labels, hist, gsum, gcnt, done, out);
}